// Round 2
// baseline (3675.274 us; speedup 1.0000x reference)
//
#include <hip/hip_runtime.h>
#include <cstdint>

// Problem constants
#define BSZ   8
#define TSEQ  2048
#define DMOD  1024
#define NROWS 16384   // B*T
#define NHEAD 16
#define DHEAD 64

// ---------- bf16 helpers ----------
__device__ __forceinline__ float bf2f(unsigned short h) {
  union { unsigned int u; float f; } a; a.u = ((unsigned int)h) << 16; return a.f;
}
__device__ __forceinline__ unsigned short f2bf(float f) {
  union { float f; unsigned int u; } a; a.f = f;
  unsigned int u = a.u;
  u += 0x7fffu + ((u >> 16) & 1u);   // RNE
  return (unsigned short)(u >> 16);
}

typedef __bf16 bf16x8 __attribute__((ext_vector_type(8)));
typedef float  f32x4  __attribute__((ext_vector_type(4)));

typedef const __attribute__((address_space(1))) void* gas_ptr;
typedef __attribute__((address_space(3))) void*       las_ptr;

__device__ __forceinline__ void gl_lds16(const void* g, void* l) {
  __builtin_amdgcn_global_load_lds((gas_ptr)g, (las_ptr)l, 16, 0, 0);
}

// ---------- weight transpose + convert: src (K x N) f32 -> dst (N x K) bf16 ----------
__global__ __launch_bounds__(256) void transpose_cvt(const float* __restrict__ src,
                                                     unsigned short* __restrict__ dst,
                                                     int K, int N) {
  __shared__ float tile[32][33];
  const int n0 = blockIdx.x * 32, k0 = blockIdx.y * 32;
  const int tx = threadIdx.x, ty = threadIdx.y;   // (32, 8)
#pragma unroll
  for (int r = 0; r < 4; ++r)
    tile[ty + r * 8][tx] = src[(size_t)(k0 + ty + r * 8) * N + n0 + tx];
  __syncthreads();
#pragma unroll
  for (int r = 0; r < 4; ++r)
    dst[(size_t)(n0 + ty + r * 8) * K + k0 + tx] = f2bf(tile[tx][ty + r * 8]);
}

__global__ __launch_bounds__(256) void concat_bias(const float* __restrict__ bq,
                                                   const float* __restrict__ bk,
                                                   const float* __restrict__ bv,
                                                   float* __restrict__ out) {
  int i = blockIdx.x * 256 + threadIdx.x;   // 4*3072
  int l = i / 3072, c = i - l * 3072;
  float v;
  if (c < 1024)       v = bq[l * 1024 + c];
  else if (c < 2048)  v = bk[l * 1024 + c - 1024];
  else                v = bv[l * 1024 + c - 2048];
  out[i] = v;
}

// ---------- embed: x = 32*x_in + sinusoidal PE (computed inline) ----------
__global__ __launch_bounds__(256) void embed_k(const float* __restrict__ xin,
                                               float* __restrict__ x) {
  const size_t row = blockIdx.x;
  const int t = blockIdx.x & (TSEQ - 1);
  const int tid = threadIdx.x;
  const int c = tid * 4;
  float4 xv = ((const float4*)(xin + row * DMOD))[tid];
  float o[4];
  float xs[4] = { xv.x, xv.y, xv.z, xv.w };
#pragma unroll
  for (int j = 0; j < 4; ++j) {
    int dd = c + j;
    int i = dd & 511;
    float fr = expf(-0.0180241494559221f * (float)i);  // -ln(10000)/511
    float ang = (float)(t + 1) * fr;
    float pe = (dd < 512) ? sinf(ang) : cosf(ang);
    o[j] = 32.0f * xs[j] + pe;
  }
  float4 ov = { o[0], o[1], o[2], o[3] };
  ((float4*)(x + row * DMOD))[tid] = ov;
}

// ---------- LayerNorm: fp32 in; bf16 out (OUTBF=1) or fp32 out (OUTBF=0) ----------
template <int OUTBF>
__global__ __launch_bounds__(256) void ln_k(const float* __restrict__ x,
                                            const float* __restrict__ gam,
                                            const float* __restrict__ bet,
                                            unsigned short* __restrict__ outH,
                                            float* __restrict__ outF) {
  const int row = blockIdx.x;
  const int tid = threadIdx.x;
  const float4 xv = ((const float4*)(x + (size_t)row * DMOD))[tid];
  float sum = xv.x + xv.y + xv.z + xv.w;
  float sq  = xv.x * xv.x + xv.y * xv.y + xv.z * xv.z + xv.w * xv.w;
#pragma unroll
  for (int o = 32; o; o >>= 1) { sum += __shfl_xor(sum, o); sq += __shfl_xor(sq, o); }
  __shared__ float s1[4], s2[4];
  const int wid = tid >> 6, lane = tid & 63;
  if (lane == 0) { s1[wid] = sum; s2[wid] = sq; }
  __syncthreads();
  sum = s1[0] + s1[1] + s1[2] + s1[3];
  sq  = s2[0] + s2[1] + s2[2] + s2[3];
  const float mu = sum * (1.0f / 1024.0f);
  const float var = sq * (1.0f / 1024.0f) - mu * mu;
  const float rs = rsqrtf(var + 1e-5f);
  const float4 g = ((const float4*)gam)[tid];
  const float4 b = ((const float4*)bet)[tid];
  float o0 = (xv.x - mu) * rs * g.x + b.x;
  float o1 = (xv.y - mu) * rs * g.y + b.y;
  float o2 = (xv.z - mu) * rs * g.z + b.z;
  float o3 = (xv.w - mu) * rs * g.w + b.w;
  if (OUTBF) {
    union { unsigned short s[4]; uint2 u; } p;
    p.s[0] = f2bf(o0); p.s[1] = f2bf(o1); p.s[2] = f2bf(o2); p.s[3] = f2bf(o3);
    ((uint2*)(outH + (size_t)row * DMOD))[tid] = p.u;
  } else {
    float4 ov = { o0, o1, o2, o3 };
    ((float4*)(outF + (size_t)row * DMOD))[tid] = ov;
  }
}

// ---------- GEMM: C(MxN) = A(M x K, row stride lda, bf16) @ Bt(NxK,bf16)^T ----------
// EPI: 1 = bias+relu -> bf16 out; 2 = bias+residual -> f32 out; 3 = bias -> bf16 out
template <int EPI>
__global__ __launch_bounds__(256) void gemm_bt(const unsigned short* __restrict__ A,
                                               const unsigned short* __restrict__ Bt,
                                               const float* __restrict__ bias,
                                               const float* resid, float* outF,
                                               unsigned short* outH,
                                               int M, int N, int K, int lda) {
  __shared__ __align__(16) unsigned short As[128 * 32];
  __shared__ __align__(16) unsigned short Bs[128 * 32];
  const int tid = threadIdx.x;
  const int wid = tid >> 6, lane = tid & 63;
  const int wm = wid >> 1, wn = wid & 1;
  const long m0 = (long)blockIdx.x * 128, n0 = (long)blockIdx.y * 128;

  f32x4 acc[4][4] = {};

  const int srow = tid >> 2;            // 0..63
  const int scol = (tid & 3) * 8;       // 0,8,16,24
  const unsigned short* Ag = A + (size_t)(m0 + srow) * lda + scol;
  const unsigned short* Bg = Bt + (size_t)(n0 + srow) * K + scol;
  char* AsW = (char*)As + wid * 1024;   // wave-uniform LDS base; lane writes base+lane*16
  char* BsW = (char*)Bs + wid * 1024;
  const size_t rowskipA = (size_t)64 * lda;
  const size_t rowskipB = (size_t)64 * K;

  const int mi = lane & 15;
  const int ko = (lane >> 4) * 8;
  const unsigned short* Ard = As + (wm * 64 + mi) * 32 + ko;
  const unsigned short* Brd = Bs + (wn * 64 + mi) * 32 + ko;

  for (int kt = 0; kt < K; kt += 32) {
    __syncthreads();
    gl_lds16(Ag + kt, AsW);
    gl_lds16(Ag + kt + rowskipA, AsW + 4096);
    gl_lds16(Bg + kt, BsW);
    gl_lds16(Bg + kt + rowskipB, BsW + 4096);
    __syncthreads();
    bf16x8 af[4], bfv[4];
#pragma unroll
    for (int i = 0; i < 4; ++i) {
      af[i]  = *(const bf16x8*)(Ard + i * 512);   // 16 rows * 32 elem
      bfv[i] = *(const bf16x8*)(Brd + i * 512);
    }
#pragma unroll
    for (int i = 0; i < 4; ++i)
#pragma unroll
      for (int j = 0; j < 4; ++j)
        acc[i][j] = __builtin_amdgcn_mfma_f32_16x16x32_bf16(af[i], bfv[j], acc[i][j], 0, 0, 0);
  }

  // epilogue: C row = (lane>>4)*4+v, col = lane&15 within each 16x16 tile (m89-verified)
  const int cm = (lane >> 4) * 4;
  const int cn = lane & 15;
#pragma unroll
  for (int i = 0; i < 4; ++i) {
    const long rbase = m0 + wm * 64 + i * 16 + cm;
#pragma unroll
    for (int j = 0; j < 4; ++j) {
      const long col = n0 + wn * 64 + j * 16 + cn;
      const float bb = bias[col];
#pragma unroll
      for (int v = 0; v < 4; ++v) {
        float val = acc[i][j][v] + bb;
        if (EPI == 1) val = fmaxf(val, 0.0f);
        if (EPI == 2) val += resid[(size_t)(rbase + v) * N + col];
        if (EPI == 2) outF[(size_t)(rbase + v) * N + col] = val;
        else          outH[(size_t)(rbase + v) * N + col] = f2bf(val);
      }
    }
  }
}

// ---------- linear attention ----------
// phase A: partial kv[d][m] = sum_t elu1(k[t,d]) * v[t,m], ksum[d] over a 256-t chunk
__global__ __launch_bounds__(256) void attn_kv_partial(const unsigned short* __restrict__ qkv,
                                                       float* __restrict__ kvp,
                                                       float* __restrict__ ksump) {
  const int bh = blockIdx.x, tc = blockIdx.y;
  const int b = bh >> 4, h = bh & 15;
  const int tid = threadIdx.x;
  const int m = tid & 63, wid = tid >> 6;
  __shared__ float ks[32][64];
  __shared__ float vs[32][64];
  float acc[16];
#pragma unroll
  for (int j = 0; j < 16; ++j) acc[j] = 0.0f;
  float ksacc = 0.0f;
  const int tt = tid >> 3;
  const int dsb = (tid & 7) * 8;
  const size_t base = ((size_t)b * TSEQ + tc * 256) * 3072;
  const int kcol = 1024 + h * 64 + dsb, vcol = 2048 + h * 64 + dsb;
  for (int sc = 0; sc < 8; ++sc) {
    __syncthreads();
    const size_t roff = base + (size_t)(sc * 32 + tt) * 3072;
    uint4 kb = *(const uint4*)(qkv + roff + kcol);
    uint4 vb = *(const uint4*)(qkv + roff + vcol);
    const unsigned int* kw = (const unsigned int*)&kb;
    const unsigned int* vw = (const unsigned int*)&vb;
#pragma unroll
    for (int w2 = 0; w2 < 4; ++w2) {
      float k0 = bf2f((unsigned short)(kw[w2] & 0xffffu));
      float k1 = bf2f((unsigned short)(kw[w2] >> 16));
      ks[tt][dsb + 2 * w2]     = (k0 > 0.f) ? k0 + 1.f : expf(k0);  // elu(k)+1
      ks[tt][dsb + 2 * w2 + 1] = (k1 > 0.f) ? k1 + 1.f : expf(k1);
      vs[tt][dsb + 2 * w2]     = bf2f((unsigned short)(vw[w2] & 0xffffu));
      vs[tt][dsb + 2 * w2 + 1] = bf2f((unsigned short)(vw[w2] >> 16));
    }
    __syncthreads();
#pragma unroll 4
    for (int t2 = 0; t2 < 32; ++t2) {
      float vv = vs[t2][m];
#pragma unroll
      for (int j = 0; j < 16; ++j) acc[j] += ks[t2][wid * 16 + j] * vv;  // broadcast read
      if (tid < 64) ksacc += ks[t2][tid];
    }
  }
  float* dst = kvp + (size_t)(tc * 128 + bh) * 4096;
#pragma unroll
  for (int j = 0; j < 16; ++j) dst[(wid * 16 + j) * 64 + m] = acc[j];
  if (tid < 64) ksump[(size_t)(tc * 128 + bh) * 64 + tid] = ksacc;
}

__global__ __launch_bounds__(256) void attn_kv_reduce(const float* __restrict__ kvp,
                                                      const float* __restrict__ ksump,
                                                      float* __restrict__ kvf,
                                                      float* __restrict__ ksumf) {
  const int bh = blockIdx.x;
  const int tid = threadIdx.x;
  for (int i = tid; i < 4096; i += 256) {
    float s = 0.f;
#pragma unroll
    for (int tc = 0; tc < 8; ++tc) s += kvp[(size_t)(tc * 128 + bh) * 4096 + i];
    kvf[(size_t)bh * 4096 + i] = s;
  }
  if (tid < 64) {
    float s = 0.f;
#pragma unroll
    for (int tc = 0; tc < 8; ++tc) s += ksump[(size_t)(tc * 128 + bh) * 64 + tid];
    ksumf[bh * 64 + tid] = s;
  }
}

// phase B: out[t,m] = (sum_d qp[d]*kv[d][m]) / (qp . ksum + eps); one wave per t.
// Output overwrites the q-slice of qkv in place (each q element read then written
// by the same thread).
__global__ __launch_bounds__(256) void attn_out_k(const unsigned short* __restrict__ qkv,
                                                  const float* __restrict__ kvf,
                                                  const float* __restrict__ ksumf,
                                                  unsigned short* __restrict__ qkvO) {
  const int bh = blockIdx.x, tcb = blockIdx.y;
  const int b = bh >> 4, h = bh & 15;
  const int tid = threadIdx.x, wid = tid >> 6, lane = tid & 63;
  __shared__ float kvs[4096];
  __shared__ float kss[64];
  __shared__ float qps[4][64];
  for (int i = tid; i < 1024; i += 256)
    ((float4*)kvs)[i] = ((const float4*)(kvf + (size_t)bh * 4096))[i];
  if (tid < 64) kss[tid] = ksumf[bh * 64 + tid];
  __syncthreads();
  for (int it = 0; it < 64; ++it) {
    const int t = tcb * 256 + wid * 64 + it;
    const size_t row = (size_t)b * TSEQ + t;
    float q = bf2f(qkv[row * 3072 + h * 64 + lane]);
    float qp = (q > 0.f) ? q + 1.f : expf(q);
    float r = qp * kss[lane];
#pragma unroll
    for (int o = 32; o; o >>= 1) r += __shfl_xor(r, o);
    const float z = 1.0f / (r + 1e-6f);
    qps[wid][lane] = qp;
    float o = 0.f;
#pragma unroll
    for (int d = 0; d < 64; ++d) o += qps[wid][d] * kvs[d * 64 + lane];
    qkvO[row * 3072 + h * 64 + lane] = f2bf(o * z);
  }
}

// ---------- launch ----------
extern "C" void kernel_launch(void* const* d_in, const int* in_sizes, int n_in,
                              void* d_out, int out_size, void* d_ws, size_t ws_size,
                              hipStream_t stream) {
  const float* x_in = (const float*)d_in[0];
  const float* Wq = (const float*)d_in[1];
  const float* bq = (const float*)d_in[2];
  const float* Wk = (const float*)d_in[3];
  const float* bk = (const float*)d_in[4];
  const float* Wv = (const float*)d_in[5];
  const float* bv = (const float*)d_in[6];
  const float* Wo = (const float*)d_in[7];
  const float* bo = (const float*)d_in[8];
  const float* W1 = (const float*)d_in[9];
  const float* b1 = (const float*)d_in[10];
  const float* W2 = (const float*)d_in[11];
  const float* b2 = (const float*)d_in[12];
  const float* ln1s = (const float*)d_in[13];
  const float* ln1b = (const float*)d_in[14];
  const float* ln2s = (const float*)d_in[15];
  const float* ln2b = (const float*)d_in[16];
  const float* lnfs = (const float*)d_in[17];
  const float* lnfb = (const float*)d_in[18];

  // Residual x lives in d_out (NROWS*DMOD f32 == out_size); final LN is in-place.
  float* x = (float*)d_out;

  // Workspace layout (~202.3 MiB total):
  char* w = (char*)d_ws;
  unsigned short* hh    = (unsigned short*)(w + 0);           //  32 MB bf16 LN out
  unsigned short* qkv   = (unsigned short*)(w + 33554432);    //  96 MB bf16 q|k|v
  unsigned short* h1    = (unsigned short*)(w + 33554432);    // 128 MB bf16 FFN mid (aliases qkv)
  unsigned short* qkvwt = (unsigned short*)(w + 167772160);   //   6 MB per-layer Wqkv^T
  unsigned short* wot   = (unsigned short*)(w + 174063616);   //   2 MB per-layer Wo^T
  unsigned short* w1t   = (unsigned short*)(w + 176160768);   //   8 MB per-layer W1^T
  unsigned short* w2t   = (unsigned short*)(w + 184549376);   //   8 MB per-layer W2^T
  float*          bqkv  = (float*)(w + 192937984);            //  48 KB
  float*          kvp   = (float*)(w + 192987136);            //  16 MB
  float*          ksump = (float*)(w + 209764352);            // 256 KB
  float*          kvf   = (float*)(w + 210026496);            //   2 MB
  float*          ksumf = (float*)(w + 212123648);            //  32 KB -> end 212156416
  (void)ws_size; (void)in_sizes; (void)n_in; (void)out_size;

  dim3 b256(256);
  dim3 tb(32, 8);
  concat_bias<<<48, b256, 0, stream>>>(bq, bk, bv, bqkv);
  embed_k<<<NROWS, b256, 0, stream>>>(x_in, x);

  for (int l = 0; l < 4; ++l) {
    // per-layer weight prep (stream-ordered after previous layer's GEMMs)
    transpose_cvt<<<dim3(32, 32), tb, 0, stream>>>(Wq + (size_t)l * 1048576, qkvwt,           1024, 1024);
    transpose_cvt<<<dim3(32, 32), tb, 0, stream>>>(Wk + (size_t)l * 1048576, qkvwt + 1048576, 1024, 1024);
    transpose_cvt<<<dim3(32, 32), tb, 0, stream>>>(Wv + (size_t)l * 1048576, qkvwt + 2097152, 1024, 1024);
    transpose_cvt<<<dim3(32, 32), tb, 0, stream>>>(Wo + (size_t)l * 1048576, wot, 1024, 1024);
    transpose_cvt<<<dim3(128, 32), tb, 0, stream>>>(W1 + (size_t)l * 4194304, w1t, 1024, 4096);
    transpose_cvt<<<dim3(32, 128), tb, 0, stream>>>(W2 + (size_t)l * 4194304, w2t, 4096, 1024);

    ln_k<1><<<NROWS, b256, 0, stream>>>(x, ln1s + l * 1024, ln1b + l * 1024, hh, nullptr);
    gemm_bt<3><<<dim3(128, 24), b256, 0, stream>>>(hh, qkvwt, bqkv + l * 3072,
                                                   nullptr, nullptr, qkv, NROWS, 3072, 1024, 1024);
    attn_kv_partial<<<dim3(128, 8), b256, 0, stream>>>(qkv, kvp, ksump);
    attn_kv_reduce<<<128, b256, 0, stream>>>(kvp, ksump, kvf, ksumf);
    attn_out_k<<<dim3(128, 8), b256, 0, stream>>>(qkv, kvf, ksumf, qkv);
    // Wo GEMM: A = attn output living in q-slice of qkv (row stride 3072)
    gemm_bt<2><<<dim3(128, 8), b256, 0, stream>>>(qkv, wot, bo + l * 1024,
                                                  x, x, nullptr, NROWS, 1024, 1024, 3072);
    ln_k<1><<<NROWS, b256, 0, stream>>>(x, ln2s + l * 1024, ln2b + l * 1024, hh, nullptr);
    gemm_bt<1><<<dim3(128, 32), b256, 0, stream>>>(hh, w1t, b1 + l * 4096,
                                                   nullptr, nullptr, h1, NROWS, 4096, 1024, 1024);
    gemm_bt<2><<<dim3(128, 8), b256, 0, stream>>>(h1, w2t, b2 + l * 1024,
                                                  x, x, nullptr, NROWS, 1024, 4096, 4096);
  }
  ln_k<0><<<NROWS, b256, 0, stream>>>(x, lnfs, lnfb, nullptr, x);
}

// Round 3
// 3447.783 us; speedup vs baseline: 1.0660x; 1.0660x over previous
//
#include <hip/hip_runtime.h>
#include <cstdint>

#define BSZ   8
#define TSEQ  2048
#define DMOD  1024
#define NROWS 16384   // B*T
#define NHEAD 16
#define DHEAD 64

// ---------- bf16 helpers ----------
__device__ __forceinline__ float bf2f(unsigned short h) {
  union { unsigned int u; float f; } a; a.u = ((unsigned int)h) << 16; return a.f;
}
__device__ __forceinline__ unsigned short f2bf(float f) {
  union { float f; unsigned int u; } a; a.f = f;
  unsigned int u = a.u;
  u += 0x7fffu + ((u >> 16) & 1u);   // RNE
  return (unsigned short)(u >> 16);
}

typedef __bf16 bf16x8 __attribute__((ext_vector_type(8)));
typedef float  f32x4  __attribute__((ext_vector_type(4)));

typedef const __attribute__((address_space(1))) void* gas_ptr;
typedef __attribute__((address_space(3))) void*       las_ptr;

__device__ __forceinline__ void gl_lds16(const void* g, void* l) {
  __builtin_amdgcn_global_load_lds((gas_ptr)g, (las_ptr)l, 16, 0, 0);
}

// ---------- weight transpose + convert: src (K x N) f32 -> dst (N x K) bf16 ----------
__global__ __launch_bounds__(256) void transpose_cvt(const float* __restrict__ src,
                                                     unsigned short* __restrict__ dst,
                                                     int K, int N) {
  __shared__ float tile[32][33];
  const int n0 = blockIdx.x * 32, k0 = blockIdx.y * 32;
  const int tx = threadIdx.x, ty = threadIdx.y;   // (32, 8)
#pragma unroll
  for (int r = 0; r < 4; ++r)
    tile[ty + r * 8][tx] = src[(size_t)(k0 + ty + r * 8) * N + n0 + tx];
  __syncthreads();
#pragma unroll
  for (int r = 0; r < 4; ++r)
    dst[(size_t)(n0 + ty + r * 8) * K + k0 + tx] = f2bf(tile[tx][ty + r * 8]);
}

__global__ __launch_bounds__(256) void concat_bias(const float* __restrict__ bq,
                                                   const float* __restrict__ bk,
                                                   const float* __restrict__ bv,
                                                   float* __restrict__ out) {
  int i = blockIdx.x * 256 + threadIdx.x;   // 4*3072
  int l = i / 3072, c = i - l * 3072;
  float v;
  if (c < 1024)       v = bq[l * 1024 + c];
  else if (c < 2048)  v = bk[l * 1024 + c - 1024];
  else                v = bv[l * 1024 + c - 2048];
  out[i] = v;
}

// ---------- embed: x = 32*x_in + sinusoidal PE (computed inline) ----------
__global__ __launch_bounds__(256) void embed_k(const float* __restrict__ xin,
                                               float* __restrict__ x) {
  const size_t row = blockIdx.x;
  const int t = blockIdx.x & (TSEQ - 1);
  const int tid = threadIdx.x;
  const int c = tid * 4;
  float4 xv = ((const float4*)(xin + row * DMOD))[tid];
  float o[4];
  float xs[4] = { xv.x, xv.y, xv.z, xv.w };
#pragma unroll
  for (int j = 0; j < 4; ++j) {
    int dd = c + j;
    int i = dd & 511;
    float fr = expf(-0.0180241494559221f * (float)i);  // -ln(10000)/511
    float ang = (float)(t + 1) * fr;
    float pe = (dd < 512) ? sinf(ang) : cosf(ang);
    o[j] = 32.0f * xs[j] + pe;
  }
  float4 ov = { o[0], o[1], o[2], o[3] };
  ((float4*)(x + row * DMOD))[tid] = ov;
}

// ---------- LayerNorm (standalone, used once after embed): fp32 in -> bf16 out ----------
__global__ __launch_bounds__(256) void ln_k(const float* __restrict__ x,
                                            const float* __restrict__ gam,
                                            const float* __restrict__ bet,
                                            unsigned short* __restrict__ outH) {
  const int row = blockIdx.x;
  const int tid = threadIdx.x;
  const float4 xv = ((const float4*)(x + (size_t)row * DMOD))[tid];
  float sum = xv.x + xv.y + xv.z + xv.w;
  float sq  = xv.x * xv.x + xv.y * xv.y + xv.z * xv.z + xv.w * xv.w;
#pragma unroll
  for (int o = 32; o; o >>= 1) { sum += __shfl_xor(sum, o); sq += __shfl_xor(sq, o); }
  __shared__ float s1[4], s2[4];
  const int wid = tid >> 6, lane = tid & 63;
  if (lane == 0) { s1[wid] = sum; s2[wid] = sq; }
  __syncthreads();
  sum = s1[0] + s1[1] + s1[2] + s1[3];
  sq  = s2[0] + s2[1] + s2[2] + s2[3];
  const float mu = sum * (1.0f / 1024.0f);
  const float var = sq * (1.0f / 1024.0f) - mu * mu;
  const float rs = rsqrtf(var + 1e-5f);
  const float4 g = ((const float4*)gam)[tid];
  const float4 b = ((const float4*)bet)[tid];
  union { unsigned short s[4]; uint2 u; } p;
  p.s[0] = f2bf((xv.x - mu) * rs * g.x + b.x);
  p.s[1] = f2bf((xv.y - mu) * rs * g.y + b.y);
  p.s[2] = f2bf((xv.z - mu) * rs * g.z + b.z);
  p.s[3] = f2bf((xv.w - mu) * rs * g.w + b.w);
  ((uint2*)(outH + (size_t)row * DMOD))[tid] = p.u;
}

// ---------- fused residual-add + LayerNorm ----------
// x (f32) += y (bf16); h = LN(x). FINAL=0: write x back + h (bf16) into outH
// (outH may alias y; reads complete before the block barrier, writes after).
// FINAL=1: write LN result as f32 to outF only (outF may alias x).
template <int FINAL>
__global__ __launch_bounds__(256) void addln_k(float* __restrict__ x,
                                               const unsigned short* y,
                                               const float* __restrict__ gam,
                                               const float* __restrict__ bet,
                                               unsigned short* outH, float* outF) {
  const int row = blockIdx.x;
  const int tid = threadIdx.x;
  float4 xv = ((const float4*)(x + (size_t)row * DMOD))[tid];
  union { uint2 u; unsigned short s[4]; } yv;
  yv.u = ((const uint2*)(y + (size_t)row * DMOD))[tid];
  xv.x += bf2f(yv.s[0]); xv.y += bf2f(yv.s[1]);
  xv.z += bf2f(yv.s[2]); xv.w += bf2f(yv.s[3]);
  float sum = xv.x + xv.y + xv.z + xv.w;
  float sq  = xv.x * xv.x + xv.y * xv.y + xv.z * xv.z + xv.w * xv.w;
#pragma unroll
  for (int o = 32; o; o >>= 1) { sum += __shfl_xor(sum, o); sq += __shfl_xor(sq, o); }
  __shared__ float s1[4], s2[4];
  const int wid = tid >> 6, lane = tid & 63;
  if (lane == 0) { s1[wid] = sum; s2[wid] = sq; }
  __syncthreads();
  sum = s1[0] + s1[1] + s1[2] + s1[3];
  sq  = s2[0] + s2[1] + s2[2] + s2[3];
  const float mu = sum * (1.0f / 1024.0f);
  const float var = sq * (1.0f / 1024.0f) - mu * mu;
  const float rs = rsqrtf(var + 1e-5f);
  const float4 g = ((const float4*)gam)[tid];
  const float4 b = ((const float4*)bet)[tid];
  float o0 = (xv.x - mu) * rs * g.x + b.x;
  float o1 = (xv.y - mu) * rs * g.y + b.y;
  float o2 = (xv.z - mu) * rs * g.z + b.z;
  float o3 = (xv.w - mu) * rs * g.w + b.w;
  if (FINAL) {
    float4 ov = { o0, o1, o2, o3 };
    ((float4*)(outF + (size_t)row * DMOD))[tid] = ov;
  } else {
    ((float4*)(x + (size_t)row * DMOD))[tid] = xv;
    union { unsigned short s[4]; uint2 u; } p;
    p.s[0] = f2bf(o0); p.s[1] = f2bf(o1); p.s[2] = f2bf(o2); p.s[3] = f2bf(o3);
    ((uint2*)(outH + (size_t)row * DMOD))[tid] = p.u;
  }
}

// ---------- GEMM: C(MxN,bf16) = A(MxK,bf16,row-stride lda) @ Bt(NxK,bf16)^T + bias ----------
// BK=64, XOR-swizzled LDS (conflict-free ds_read_b128), LDS-staged coalesced epilogue.
// RELU=1 applies max(0,.) before the bf16 convert. Output row stride == N.
template <int RELU>
__global__ __launch_bounds__(256) void gemm_bt(const unsigned short* __restrict__ A,
                                               const unsigned short* __restrict__ Bt,
                                               const float* __restrict__ bias,
                                               unsigned short* __restrict__ outH,
                                               int M, int N, int K, int lda) {
  __shared__ __align__(16) unsigned short sm[16384];   // 32 KB: As | Bs; reused as Ct
  unsigned short* As = sm;
  unsigned short* Bs = sm + 8192;
  const int tid = threadIdx.x;
  const int wid = tid >> 6, lane = tid & 63;
  const int wm = wid >> 1, wn = wid & 1;
  const long m0 = (long)blockIdx.x * 128, n0 = (long)blockIdx.y * 128;

  f32x4 acc[4][4] = {};

  // staging: lane stages global (row = p*32 + tid>>3, chunk = (tid&7)^((tid>>3)&7)),
  // landing at LDS slot tid&7 of that row => lds addr = wave_base + lane*16 (HW constraint).
  const int srow = tid >> 3;                    // 0..31
  const int cswz = (tid & 7) ^ (srow & 7);      // swizzled 16B-chunk index
  const unsigned short* Ag = A + (size_t)(m0 + srow) * lda + cswz * 8;
  const unsigned short* Bg = Bt + (size_t)(n0 + srow) * K + cswz * 8;
  char* AsW = (char*)As + wid * 1024;
  char* BsW = (char*)Bs + wid * 1024;
  const size_t a32 = (size_t)32 * lda, b32 = (size_t)32 * K;

  // fragment reads: A[m=lane&15][k=(lane>>4)*8+j]; chunk c=(lane>>4)+4s at slot c^(row&7)
  const int fr = lane & 15;
  const int aswz = (((lane >> 4) ^ (lane & 7)) << 4);   // byte offset of slot, s=0
  const int arow = (wm * 64 + fr) << 7;                 // *128 bytes per row
  const int brow = (wn * 64 + fr) << 7;
  const char* smc = (const char*)sm;
  const char* smcB = (const char*)(sm + 8192);

  for (int kt = 0; kt < K; kt += 64) {
    __syncthreads();
#pragma unroll
    for (int p = 0; p < 4; ++p) {
      gl_lds16(Ag + kt + (size_t)p * a32, AsW + p * 4096);
      gl_lds16(Bg + kt + (size_t)p * b32, BsW + p * 4096);
    }
    __syncthreads();
#pragma unroll
    for (int s = 0; s < 2; ++s) {
      const int offs = aswz ^ (s << 6);
      bf16x8 af[4], bfv[4];
#pragma unroll
      for (int i = 0; i < 4; ++i) {
        af[i]  = *(const bf16x8*)(smc  + arow + i * 2048 + offs);
        bfv[i] = *(const bf16x8*)(smcB + brow + i * 2048 + offs);
      }
#pragma unroll
      for (int i = 0; i < 4; ++i)
#pragma unroll
        for (int j = 0; j < 4; ++j)
          acc[i][j] = __builtin_amdgcn_mfma_f32_16x16x32_bf16(af[i], bfv[j], acc[i][j], 0, 0, 0);
    }
  }

  // epilogue: stage 128x64 bf16 half-tiles in LDS (stride 72), store 128B segments.
  // C layout per 16x16 tile: row=(lane>>4)*4+v, col=lane&15 (m89-verified).
  const int cq = lane >> 4, cn = lane & 15;
#pragma unroll
  for (int p = 0; p < 2; ++p) {
    __syncthreads();
    if (wn == p) {
#pragma unroll
      for (int i = 0; i < 4; ++i)
#pragma unroll
        for (int j = 0; j < 4; ++j) {
          const float bb = bias[n0 + p * 64 + j * 16 + cn];
#pragma unroll
          for (int v = 0; v < 4; ++v) {
            float val = acc[i][j][v] + bb;
            if (RELU) val = fmaxf(val, 0.0f);
            sm[(wm * 64 + i * 16 + cq * 4 + v) * 72 + j * 16 + cn] = f2bf(val);
          }
        }
    }
    __syncthreads();
#pragma unroll
    for (int q = 0; q < 4; ++q) {
      const int idx = q * 256 + tid;
      const int row = idx >> 3, cc = idx & 7;
      uint4 valq = *(const uint4*)(sm + row * 72 + cc * 8);
      *(uint4*)(outH + (size_t)(m0 + row) * N + n0 + p * 64 + cc * 8) = valq;
    }
  }
}

// ---------- linear attention ----------
// phase A: partial kv[d][m] = sum_t elu1(k[t,d]) * v[t,m], ksum[d] over a 256-t chunk
__global__ __launch_bounds__(256) void attn_kv_partial(const unsigned short* __restrict__ qkv,
                                                       float* __restrict__ kvp,
                                                       float* __restrict__ ksump) {
  const int bh = blockIdx.x, tc = blockIdx.y;
  const int b = bh >> 4, h = bh & 15;
  const int tid = threadIdx.x;
  const int m = tid & 63, wid = tid >> 6;
  __shared__ float ks[32][64];
  __shared__ float vs[32][64];
  float acc[16];
#pragma unroll
  for (int j = 0; j < 16; ++j) acc[j] = 0.0f;
  float ksacc = 0.0f;
  const int tt = tid >> 3;
  const int dsb = (tid & 7) * 8;
  const size_t base = ((size_t)b * TSEQ + tc * 256) * 3072;
  const int kcol = 1024 + h * 64 + dsb, vcol = 2048 + h * 64 + dsb;
  for (int sc = 0; sc < 8; ++sc) {
    __syncthreads();
    const size_t roff = base + (size_t)(sc * 32 + tt) * 3072;
    uint4 kb = *(const uint4*)(qkv + roff + kcol);
    uint4 vb = *(const uint4*)(qkv + roff + vcol);
    const unsigned int* kw = (const unsigned int*)&kb;
    const unsigned int* vw = (const unsigned int*)&vb;
#pragma unroll
    for (int w2 = 0; w2 < 4; ++w2) {
      float k0 = bf2f((unsigned short)(kw[w2] & 0xffffu));
      float k1 = bf2f((unsigned short)(kw[w2] >> 16));
      ks[tt][dsb + 2 * w2]     = (k0 > 0.f) ? k0 + 1.f : expf(k0);  // elu(k)+1
      ks[tt][dsb + 2 * w2 + 1] = (k1 > 0.f) ? k1 + 1.f : expf(k1);
      vs[tt][dsb + 2 * w2]     = bf2f((unsigned short)(vw[w2] & 0xffffu));
      vs[tt][dsb + 2 * w2 + 1] = bf2f((unsigned short)(vw[w2] >> 16));
    }
    __syncthreads();
#pragma unroll 4
    for (int t2 = 0; t2 < 32; ++t2) {
      float vv = vs[t2][m];
#pragma unroll
      for (int j = 0; j < 16; ++j) acc[j] += ks[t2][wid * 16 + j] * vv;  // broadcast read
      if (tid < 64) ksacc += ks[t2][tid];
    }
  }
  float* dst = kvp + (size_t)(tc * 128 + bh) * 4096;
#pragma unroll
  for (int j = 0; j < 16; ++j) dst[(wid * 16 + j) * 64 + m] = acc[j];
  if (tid < 64) ksump[(size_t)(tc * 128 + bh) * 64 + tid] = ksacc;
}

__global__ __launch_bounds__(256) void attn_kv_reduce(const float* __restrict__ kvp,
                                                      const float* __restrict__ ksump,
                                                      float* __restrict__ kvf,
                                                      float* __restrict__ ksumf) {
  const int bh = blockIdx.x;
  const int tid = threadIdx.x;
  for (int i = tid; i < 4096; i += 256) {
    float s = 0.f;
#pragma unroll
    for (int tc = 0; tc < 8; ++tc) s += kvp[(size_t)(tc * 128 + bh) * 4096 + i];
    kvf[(size_t)bh * 4096 + i] = s;
  }
  if (tid < 64) {
    float s = 0.f;
#pragma unroll
    for (int tc = 0; tc < 8; ++tc) s += ksump[(size_t)(tc * 128 + bh) * 64 + tid];
    ksumf[bh * 64 + tid] = s;
  }
}

// phase B: out[t,m] = (sum_d qp[d]*kv[d][m]) / (qp . ksum + eps); one wave per t.
// Output overwrites the q-slice of qkv in place.
__global__ __launch_bounds__(256) void attn_out_k(const unsigned short* __restrict__ qkv,
                                                  const float* __restrict__ kvf,
                                                  const float* __restrict__ ksumf,
                                                  unsigned short* __restrict__ qkvO) {
  const int bh = blockIdx.x, tcb = blockIdx.y;
  const int b = bh >> 4, h = bh & 15;
  const int tid = threadIdx.x, wid = tid >> 6, lane = tid & 63;
  __shared__ float kvs[4096];
  __shared__ float kss[64];
  __shared__ float qps[4][64];
  for (int i = tid; i < 1024; i += 256)
    ((float4*)kvs)[i] = ((const float4*)(kvf + (size_t)bh * 4096))[i];
  if (tid < 64) kss[tid] = ksumf[bh * 64 + tid];
  __syncthreads();
  for (int it = 0; it < 64; ++it) {
    const int t = tcb * 256 + wid * 64 + it;
    const size_t row = (size_t)b * TSEQ + t;
    float q = bf2f(qkv[row * 3072 + h * 64 + lane]);
    float qp = (q > 0.f) ? q + 1.f : expf(q);
    float r = qp * kss[lane];
#pragma unroll
    for (int o = 32; o; o >>= 1) r += __shfl_xor(r, o);
    const float z = 1.0f / (r + 1e-6f);
    qps[wid][lane] = qp;
    float o = 0.f;
#pragma unroll
    for (int d = 0; d < 64; ++d) o += qps[wid][d] * kvs[d * 64 + lane];
    qkvO[row * 3072 + h * 64 + lane] = f2bf(o * z);
  }
}

// ---------- launch ----------
extern "C" void kernel_launch(void* const* d_in, const int* in_sizes, int n_in,
                              void* d_out, int out_size, void* d_ws, size_t ws_size,
                              hipStream_t stream) {
  const float* x_in = (const float*)d_in[0];
  const float* Wq = (const float*)d_in[1];
  const float* bq = (const float*)d_in[2];
  const float* Wk = (const float*)d_in[3];
  const float* bk = (const float*)d_in[4];
  const float* Wv = (const float*)d_in[5];
  const float* bv = (const float*)d_in[6];
  const float* Wo = (const float*)d_in[7];
  const float* bo = (const float*)d_in[8];
  const float* W1 = (const float*)d_in[9];
  const float* b1 = (const float*)d_in[10];
  const float* W2 = (const float*)d_in[11];
  const float* b2 = (const float*)d_in[12];
  const float* ln1s = (const float*)d_in[13];
  const float* ln1b = (const float*)d_in[14];
  const float* ln2s = (const float*)d_in[15];
  const float* ln2b = (const float*)d_in[16];
  const float* lnfs = (const float*)d_in[17];
  const float* lnfb = (const float*)d_in[18];

  // Residual x lives in d_out (NROWS*DMOD f32); final addln<1> writes LN result in-place.
  float* x = (float*)d_out;

  // Workspace layout (~202.3 MiB):
  char* w = (char*)d_ws;
  unsigned short* hh    = (unsigned short*)(w + 0);           //  32 MB bf16 LN out / y
  unsigned short* qkv   = (unsigned short*)(w + 33554432);    //  96 MB bf16 q|k|v
  unsigned short* h1    = (unsigned short*)(w + 33554432);    // 128 MB bf16 FFN mid (aliases qkv)
  unsigned short* qkvwt = (unsigned short*)(w + 167772160);   //   6 MB per-layer Wqkv^T
  unsigned short* wot   = (unsigned short*)(w + 174063616);   //   2 MB per-layer Wo^T
  unsigned short* w1t   = (unsigned short*)(w + 176160768);   //   8 MB per-layer W1^T
  unsigned short* w2t   = (unsigned short*)(w + 184549376);   //   8 MB per-layer W2^T
  float*          bqkv  = (float*)(w + 192937984);            //  48 KB
  float*          kvp   = (float*)(w + 192987136);            //  16 MB
  float*          ksump = (float*)(w + 209764352);            // 256 KB
  float*          kvf   = (float*)(w + 210026496);            //   2 MB
  float*          ksumf = (float*)(w + 212123648);            //  32 KB
  (void)ws_size; (void)in_sizes; (void)n_in; (void)out_size;

  dim3 b256(256);
  dim3 tb(32, 8);
  concat_bias<<<48, b256, 0, stream>>>(bq, bk, bv, bqkv);
  embed_k<<<NROWS, b256, 0, stream>>>(x_in, x);
  ln_k<<<NROWS, b256, 0, stream>>>(x, ln1s, ln1b, hh);

  for (int l = 0; l < 4; ++l) {
    transpose_cvt<<<dim3(32, 32), tb, 0, stream>>>(Wq + (size_t)l * 1048576, qkvwt,           1024, 1024);
    transpose_cvt<<<dim3(32, 32), tb, 0, stream>>>(Wk + (size_t)l * 1048576, qkvwt + 1048576, 1024, 1024);
    transpose_cvt<<<dim3(32, 32), tb, 0, stream>>>(Wv + (size_t)l * 1048576, qkvwt + 2097152, 1024, 1024);
    transpose_cvt<<<dim3(32, 32), tb, 0, stream>>>(Wo + (size_t)l * 1048576, wot, 1024, 1024);
    transpose_cvt<<<dim3(128, 32), tb, 0, stream>>>(W1 + (size_t)l * 4194304, w1t, 1024, 4096);
    transpose_cvt<<<dim3(32, 128), tb, 0, stream>>>(W2 + (size_t)l * 4194304, w2t, 4096, 1024);

    // QKV projection (reads hh = LN1 output)
    gemm_bt<0><<<dim3(128, 24), b256, 0, stream>>>(hh, qkvwt, bqkv + l * 3072, qkv,
                                                   NROWS, 3072, 1024, 1024);
    attn_kv_partial<<<dim3(128, 8), b256, 0, stream>>>(qkv, kvp, ksump);
    attn_kv_reduce<<<128, b256, 0, stream>>>(kvp, ksump, kvf, ksumf);
    attn_out_k<<<dim3(128, 8), b256, 0, stream>>>(qkv, kvf, ksumf, qkv);
    // Wo: A = attn output in q-slice of qkv (lda 3072); y -> hh (dead after QKV gemm)
    gemm_bt<0><<<dim3(128, 8), b256, 0, stream>>>(qkv, wot, bo + l * 1024, hh,
                                                  NROWS, 1024, 1024, 3072);
    addln_k<0><<<NROWS, b256, 0, stream>>>(x, hh, ln2s + l * 1024, ln2b + l * 1024, hh, nullptr);
    // FFN
    gemm_bt<1><<<dim3(128, 32), b256, 0, stream>>>(hh, w1t, b1 + l * 4096, h1,
                                                   NROWS, 4096, 1024, 1024);
    gemm_bt<0><<<dim3(128, 8), b256, 0, stream>>>(h1, w2t, b2 + l * 1024, hh,
                                                  NROWS, 1024, 4096, 4096);
    if (l < 3)
      addln_k<0><<<NROWS, b256, 0, stream>>>(x, hh, ln1s + (l + 1) * 1024, ln1b + (l + 1) * 1024,
                                             hh, nullptr);
    else
      addln_k<1><<<NROWS, b256, 0, stream>>>(x, hh, lnfs, lnfb, nullptr, x);
  }
}